// Round 12
// baseline (4235.968 us; speedup 1.0000x reference)
//
#include <hip/hip_runtime.h>

typedef unsigned short u16;
typedef unsigned int u32;
typedef __attribute__((ext_vector_type(8))) short bf16x8;
typedef __attribute__((ext_vector_type(4))) float f32x4;

#define KDIM   512
#define NROWS  1024
#define NCLS   100000
#define CPAD   100096   // 782*128
#define NSTRIP 782      // 128-wide column strips
#define NMT    8        // 1024/128
#define NWG    (NSTRIP*NMT)   // 6256

#define COS_M_C   0.8775825618903728f
#define SIN_M_C   0.4794255386042030f
#define THRESH_C  (-0.8775825618903728f)
#define MM_C      0.2397127693021015f
#define S_C       64.0f

__device__ __forceinline__ u16 f2bf(float f) {
    u32 x = __float_as_uint(f);
    x += 0x7fffu + ((x >> 16) & 1u);   // RNE
    return (u16)(x >> 16);
}
__device__ __forceinline__ float bf2f(u16 u) {
    return __uint_as_float(((u32)u) << 16);
}
__device__ __forceinline__ u32 pack2(float a, float b) {
    return (u32)f2bf(a) | ((u32)f2bf(b) << 16);
}

// Image geometry (R8-validated, SQ_LDS_BANK_CONFLICT == 0): per (tile, kt)
// an 8 KB block = 128 rows x 32 k bf16 = 64 lines of 128 B. Chunk (r,q) at
// line r>>1, slot ((r&1)*4 + q + (r>>1)) & 7. Fragment m stride = 512 u16.
__device__ __forceinline__ int imgoff(int r, int q) {   // u16 units
    return (r >> 1) * 64 + ((((r & 1) << 2) + q + (r >> 1)) & 7) * 8;
}

__device__ __forceinline__ void gld16(const void* g, void* l) {
    __builtin_amdgcn_global_load_lds(
        (const __attribute__((address_space(1))) void*)g,
        (__attribute__((address_space(3))) void*)l, 16, 0, 0);
}

// ---------------- kernel 1: row-normalize embeddings ----------------
__global__ __launch_bounds__(64)
void norm_emb_k(const float* __restrict__ emb, float* __restrict__ Af,
                u16* __restrict__ Aw) {
    const int i = blockIdx.x, l = threadIdx.x;
    const float* e = emb + i * KDIM;
    float4 v0 = *(const float4*)(e + l * 8);
    float4 v1 = *(const float4*)(e + l * 8 + 4);
    float s = v0.x*v0.x + v0.y*v0.y + v0.z*v0.z + v0.w*v0.w
            + v1.x*v1.x + v1.y*v1.y + v1.z*v1.z + v1.w*v1.w;
    #pragma unroll
    for (int o = 1; o < 64; o <<= 1) s += __shfl_xor(s, o);
    float inv = rsqrtf(s);
    float4 n0 = make_float4(v0.x*inv, v0.y*inv, v0.z*inv, v0.w*inv);
    float4 n1 = make_float4(v1.x*inv, v1.y*inv, v1.z*inv, v1.w*inv);
    *(float4*)(Af + i*KDIM + l*8)     = n0;
    *(float4*)(Af + i*KDIM + l*8 + 4) = n1;
    const int mt = i >> 7, row = i & 127;
    uint4 w;
    w.x = pack2(n0.x, n0.y);
    w.y = pack2(n0.z, n0.w);
    w.z = pack2(n1.x, n1.y);
    w.w = pack2(n1.z, n1.w);
    *(uint4*)(Aw + mt*65536 + (l>>2)*4096 + imgoff(row, l & 3)) = w;
}

// ------- kernel 2: transpose+convert W -> Bn image + column norms -------
__global__ __launch_bounds__(128)
void transpose_norm_k(const float* __restrict__ Kg, u16* __restrict__ Bn,
                      float* __restrict__ kinv) {
    __shared__ float Ls[32 * 132];
    const int t  = threadIdx.x;
    const int jb = blockIdx.x * 128;
    const int j  = jb + t;
    u16* bstrip = Bn + (size_t)blockIdx.x * 65536;
    float acc = 0.f;
    for (int kc = 0; kc < 16; ++kc) {
        #pragma unroll
        for (int it = 0; it < 8; ++it) {
            int fid  = it * 128 + t;
            int r    = fid >> 5;
            int c4   = (fid & 31) * 4;
            int gcol = jb + c4;
            float4 v;
            if (gcol + 3 < NCLS) {
                v = *(const float4*)(Kg + (kc*32 + r) * NCLS + gcol);
            } else {
                v.x = (gcol + 0 < NCLS) ? Kg[(kc*32 + r)*NCLS + gcol + 0] : 0.f;
                v.y = (gcol + 1 < NCLS) ? Kg[(kc*32 + r)*NCLS + gcol + 1] : 0.f;
                v.z = (gcol + 2 < NCLS) ? Kg[(kc*32 + r)*NCLS + gcol + 2] : 0.f;
                v.w = (gcol + 3 < NCLS) ? Kg[(kc*32 + r)*NCLS + gcol + 3] : 0.f;
            }
            *(float4*)(Ls + r * 132 + c4) = v;
        }
        __syncthreads();
        #pragma unroll
        for (int q = 0; q < 4; ++q) {
            u16 u[8];
            #pragma unroll
            for (int e = 0; e < 8; ++e) {
                float v = Ls[(q*8 + e) * 132 + t];
                acc += v * v;
                u[e] = f2bf(v);
            }
            uint4 w;
            w.x = (u32)u[0] | ((u32)u[1] << 16);
            w.y = (u32)u[2] | ((u32)u[3] << 16);
            w.z = (u32)u[4] | ((u32)u[5] << 16);
            w.w = (u32)u[6] | ((u32)u[7] << 16);
            *(uint4*)(bstrip + kc*4096 + imgoff(t, q)) = w;
        }
        __syncthreads();
    }
    kinv[j] = rsqrtf(fmaxf(acc, 1e-30f));
}

// ---------------- kernel 3: per-row target logit & margins ----------------
__global__ __launch_bounds__(64)
void target_k(const float* __restrict__ Af, const u16* __restrict__ Bn,
              const float* __restrict__ kinv, const int* __restrict__ label,
              float* __restrict__ tgt, float* __restrict__ ctm,
              float* __restrict__ fin) {
    const int i = blockIdx.x, l = threadIdx.x;
    const int lab = label[i];
    float4 a0 = *(const float4*)(Af + i * KDIM + l * 8);
    float4 a1 = *(const float4*)(Af + i * KDIM + l * 8 + 4);
    uint4 bv = *(const uint4*)(Bn + (size_t)(lab >> 7) * 65536
               + (l >> 2) * 4096 + imgoff(lab & 127, l & 3));
    float d = a0.x * bf2f((u16)(bv.x & 0xffff)) + a0.y * bf2f((u16)(bv.x >> 16))
            + a0.z * bf2f((u16)(bv.y & 0xffff)) + a0.w * bf2f((u16)(bv.y >> 16))
            + a1.x * bf2f((u16)(bv.z & 0xffff)) + a1.y * bf2f((u16)(bv.z >> 16))
            + a1.z * bf2f((u16)(bv.w & 0xffff)) + a1.w * bf2f((u16)(bv.w >> 16));
    #pragma unroll
    for (int o = 1; o < 64; o <<= 1) d += __shfl_xor(d, o);
    if (l == 0) {
        float c = d * kinv[lab];
        c = fminf(fmaxf(c, -1.f), 1.f);
        tgt[i] = c;
        float sn = sqrtf(fmaxf(1.f - c*c, 0.f));
        float cm = c * COS_M_C - sn * SIN_M_C;
        ctm[i] = cm;
        fin[i] = (c > THRESH_C) ? cm : (c - MM_C);
    }
}

// ---------------- kernel 4: t_new scalar ----------------
__global__ __launch_bounds__(256)
void tnew_k(const float* __restrict__ tgt, const float* __restrict__ tin,
            float* __restrict__ tnw) {
    __shared__ float red[256];
    const int t = threadIdx.x;
    float s = tgt[t] + tgt[t + 256] + tgt[t + 512] + tgt[t + 768];
    red[t] = s;
    __syncthreads();
    for (int o = 128; o > 0; o >>= 1) {
        if (t < o) red[t] += red[t + o];
        __syncthreads();
    }
    if (t == 0) tnw[0] = red[0] * (0.01f / 1024.f) + 0.99f * tin[0];
}

// ================== GEMM body, ablation-templated ==================
// MODE flags
#define F_STG 1   // stage in loop
#define F_RD  2   // ds_read fragments
#define F_MM  4   // MFMA
#define F_EPI 8   // epilogue + stores

#define GEMM_ARGS \
    const u16* __restrict__ A, const u16* __restrict__ B, \
    const float* __restrict__ kinv, const float* __restrict__ ctm, \
    const float* __restrict__ fin, const int* __restrict__ label, \
    const float* __restrict__ tnwp, float* __restrict__ out

template<int MODE, int REPS>
__device__ __forceinline__ void gemm_body(GEMM_ARGS) {
    __shared__ __align__(16) u16 As[2][4096];
    __shared__ __align__(16) u16 Bs[2][4096];
    const int tid  = threadIdx.x;
    const int wave = tid >> 6, lane = tid & 63;

    const int L  = blockIdx.x;
    const int w  = (L & 7) * NSTRIP + (L >> 3);
    const int mt = w & 7;
    const int cs = w >> 3;
    const int m0 = mt * 128;
    const int j0 = cs * 128;
    const int wr = (wave >> 1) * 64;
    const int wc = (wave & 1) * 64;

    f32x4 acc[4][4] = {};

    const u16* gA = A + mt * 65536 + tid * 8;
    const u16* gB = B + (size_t)cs * 65536 + tid * 8;

    const int lr = lane & 15, q = lane >> 4;
    const int aBase = imgoff(wr + lr, q);
    const int bBase = imgoff(wc + lr, q);

#define STAGE(b, kt) do {                                        \
    gld16(gA + (kt)*4096,        &As[b][tid*8]);                 \
    gld16(gA + (kt)*4096 + 2048, &As[b][tid*8 + 2048]);          \
    gld16(gB + (kt)*4096,        &Bs[b][tid*8]);                 \
    gld16(gB + (kt)*4096 + 2048, &Bs[b][tid*8 + 2048]);          \
} while (0)

    if constexpr (!(MODE & F_STG)) {
        STAGE(0, 0);
        STAGE(1, 1);
        asm volatile("s_waitcnt vmcnt(0)" ::: "memory");
    }

    #pragma unroll 1
    for (int rep = 0; rep < REPS; ++rep) {
        if constexpr (MODE & F_STG) STAGE(0, 0);
        #pragma unroll 2
        for (int kt = 0; kt < 16; ++kt) {
            const int cur = kt & 1;
            if (kt < 15) {
                if constexpr (MODE & F_STG) STAGE(cur ^ 1, kt + 1);
                asm volatile("s_waitcnt vmcnt(4)" ::: "memory");
            } else {
                asm volatile("s_waitcnt vmcnt(0)" ::: "memory");
            }
            __builtin_amdgcn_s_barrier();

            bf16x8 af[4], bfr[4];
            if constexpr (MODE & F_RD) {
                #pragma unroll
                for (int m = 0; m < 4; ++m)
                    af[m] = *(const bf16x8*)(As[cur] + aBase + m * 512);
                #pragma unroll
                for (int n = 0; n < 4; ++n)
                    bfr[n] = *(const bf16x8*)(Bs[cur] + bBase + n * 512);
                asm volatile("s_waitcnt lgkmcnt(0)" ::: "memory");
                __builtin_amdgcn_sched_barrier(0);
            }
            __builtin_amdgcn_s_barrier();

            if constexpr (MODE & F_MM) {
                #pragma unroll
                for (int m = 0; m < 4; ++m)
                    #pragma unroll
                    for (int n = 0; n < 4; ++n)
                        acc[m][n] = __builtin_amdgcn_mfma_f32_16x16x32_bf16(
                                        af[m], bfr[n], acc[m][n], 0, 0, 0);
            } else if constexpr (MODE & F_RD) {
                // rule 17: keep ds_reads live without MFMA
                #pragma unroll
                for (int m = 0; m < 4; ++m)
                    asm volatile("" :: "v"(af[m]), "v"(bfr[m]));
            }
        }
    }
#undef STAGE

    if constexpr (MODE & F_EPI) {
        const float tnew = *tnwp;
        const int colbase = j0 + wc + lr;
        float kv[4];
        int cols[4];
        #pragma unroll
        for (int n = 0; n < 4; ++n) {
            cols[n] = colbase + n * 16;
            kv[n] = kinv[cols[n]];
        }
        #pragma unroll
        for (int m = 0; m < 4; ++m) {
            const int rb = m0 + wr + m * 16 + q * 4;
            #pragma unroll
            for (int r = 0; r < 4; ++r) {
                const int row = rb + r;
                const int lab = label[row];
                const float ct = ctm[row];
                const float fv = fin[row];
                float* orow = out + (size_t)row * NCLS;
                #pragma unroll
                for (int n = 0; n < 4; ++n) {
                    float c = acc[m][n][r] * kv[n];
                    c = fminf(fmaxf(c, -1.f), 1.f);
                    float v = (c > ct) ? c * (tnew + c) : c;
                    v = (cols[n] == lab) ? fv : v;
                    if (cols[n] < NCLS)
                        orow[cols[n]] = v * S_C;
                }
            }
        }
    } else {
        // rule 17: keep acc live, no stores
        #pragma unroll
        for (int m = 0; m < 4; ++m)
            #pragma unroll
            for (int n = 0; n < 4; ++n)
                asm volatile("" :: "v"(acc[m][n]));
    }
}

#define REPS_P 16

// skeleton only: stage + vmcnt + barriers
__global__ __launch_bounds__(256, 4)
void p_noread(GEMM_ARGS) { gemm_body<F_STG, REPS_P>(A,B,kinv,ctm,fin,label,tnwp,out); }

// + ds_read (no MFMA)
__global__ __launch_bounds__(256, 4)
void p_nomfma(GEMM_ARGS) { gemm_body<F_STG|F_RD, REPS_P>(A,B,kinv,ctm,fin,label,tnwp,out); }

// ds_read + MFMA (staged once, no in-loop gld16)
__global__ __launch_bounds__(256, 4)
void p_nostage(GEMM_ARGS) { gemm_body<F_RD|F_MM, REPS_P>(A,B,kinv,ctm,fin,label,tnwp,out); }

// full K-loop, no epilogue
__global__ __launch_bounds__(256, 4)
void p_core(GEMM_ARGS) { gemm_body<F_STG|F_RD|F_MM, REPS_P>(A,B,kinv,ctm,fin,label,tnwp,out); }

// exact R8 production kernel (REPS=1, epilogue) — runs LAST, validated writer
__global__ __launch_bounds__(256, 4)
void g_full(GEMM_ARGS) { gemm_body<F_STG|F_RD|F_MM|F_EPI, 1>(A,B,kinv,ctm,fin,label,tnwp,out); }

extern "C" void kernel_launch(void* const* d_in, const int* in_sizes, int n_in,
                              void* d_out, int out_size, void* d_ws, size_t ws_size,
                              hipStream_t stream) {
    const float* emb = (const float*)d_in[0];
    const float* Kg  = (const float*)d_in[1];
    const float* tin = (const float*)d_in[2];
    const int*   lab = (const int*)d_in[3];
    float* out = (float*)d_out;

    char* w = (char*)d_ws;
    u16*   Bn   = (u16*)w;
    u16*   Aw   = (u16*)(w + 102498304);
    float* Af   = (float*)(w + 103546880);
    float* kinv = (float*)(w + 105644032);
    float* tgt  = (float*)(w + 106044416);
    float* ctmv = (float*)(w + 106048512);
    float* finv = (float*)(w + 106052608);
    float* tnw  = (float*)(w + 106056704);

    norm_emb_k<<<NROWS, 64, 0, stream>>>(emb, Af, Aw);
    transpose_norm_k<<<NSTRIP, 128, 0, stream>>>(Kg, Bn, kinv);
    target_k<<<NROWS, 64, 0, stream>>>(Af, Bn, kinv, lab, tgt, ctmv, finv);
    tnew_k<<<1, 256, 0, stream>>>(tgt, tin, tnw);

    // Ablation probes (distinct names, x16 reps -> all visible in top-5).
    p_noread <<<NWG, 256, 0, stream>>>(Aw, Bn, kinv, ctmv, finv, lab, tnw, out);
    p_nomfma <<<NWG, 256, 0, stream>>>(Aw, Bn, kinv, ctmv, finv, lab, tnw, out);
    p_nostage<<<NWG, 256, 0, stream>>>(Aw, Bn, kinv, ctmv, finv, lab, tnw, out);
    p_core   <<<NWG, 256, 0, stream>>>(Aw, Bn, kinv, ctmv, finv, lab, tnw, out);
    // production kernel, validated writer, runs last
    g_full   <<<NWG, 256, 0, stream>>>(Aw, Bn, kinv, ctmv, finv, lab, tnw, out);
}

// Round 13
// 586.384 us; speedup vs baseline: 7.2239x; 7.2239x over previous
//
#include <hip/hip_runtime.h>

typedef unsigned short u16;
typedef unsigned int u32;
typedef __attribute__((ext_vector_type(8))) short bf16x8;
typedef __attribute__((ext_vector_type(4))) float f32x4;

#define KDIM   512
#define NROWS  1024
#define NCLS   100000
#define CPAD   100096   // 782*128
#define NSTRIP 782      // 128-wide column strips
#define NMT    8        // 1024/128
#define NWG    (NSTRIP*NMT)   // 6256

#define COS_M_C   0.8775825618903728f
#define SIN_M_C   0.4794255386042030f
#define THRESH_C  (-0.8775825618903728f)
#define MM_C      0.2397127693021015f
#define S_C       64.0f

__device__ __forceinline__ u16 f2bf(float f) {
    u32 x = __float_as_uint(f);
    x += 0x7fffu + ((x >> 16) & 1u);   // RNE
    return (u16)(x >> 16);
}
__device__ __forceinline__ float bf2f(u16 u) {
    return __uint_as_float(((u32)u) << 16);
}
__device__ __forceinline__ u32 pack2(float a, float b) {
    return (u32)f2bf(a) | ((u32)f2bf(b) << 16);
}

// Image geometry (R8-validated, SQ_LDS_BANK_CONFLICT == 0): per (tile, kt)
// an 8 KB block = 128 rows x 32 k bf16 = 64 lines of 128 B. Chunk (r,q) at
// line r>>1, slot ((r&1)*4 + q + (r>>1)) & 7. Fragment m stride = 512 u16.
__device__ __forceinline__ int imgoff(int r, int q) {   // u16 units
    return (r >> 1) * 64 + ((((r & 1) << 2) + q + (r >> 1)) & 7) * 8;
}

__device__ __forceinline__ void gld16(const void* g, void* l) {
    __builtin_amdgcn_global_load_lds(
        (const __attribute__((address_space(1))) void*)g,
        (__attribute__((address_space(3))) void*)l, 16, 0, 0);
}

// ---------------- kernel 1: row-normalize embeddings ----------------
__global__ __launch_bounds__(64)
void norm_emb_k(const float* __restrict__ emb, float* __restrict__ Af,
                u16* __restrict__ Aw) {
    const int i = blockIdx.x, l = threadIdx.x;
    const float* e = emb + i * KDIM;
    float4 v0 = *(const float4*)(e + l * 8);
    float4 v1 = *(const float4*)(e + l * 8 + 4);
    float s = v0.x*v0.x + v0.y*v0.y + v0.z*v0.z + v0.w*v0.w
            + v1.x*v1.x + v1.y*v1.y + v1.z*v1.z + v1.w*v1.w;
    #pragma unroll
    for (int o = 1; o < 64; o <<= 1) s += __shfl_xor(s, o);
    float inv = rsqrtf(s);
    float4 n0 = make_float4(v0.x*inv, v0.y*inv, v0.z*inv, v0.w*inv);
    float4 n1 = make_float4(v1.x*inv, v1.y*inv, v1.z*inv, v1.w*inv);
    *(float4*)(Af + i*KDIM + l*8)     = n0;
    *(float4*)(Af + i*KDIM + l*8 + 4) = n1;
    const int mt = i >> 7, row = i & 127;
    uint4 w;
    w.x = pack2(n0.x, n0.y);
    w.y = pack2(n0.z, n0.w);
    w.z = pack2(n1.x, n1.y);
    w.w = pack2(n1.z, n1.w);
    *(uint4*)(Aw + mt*65536 + (l>>2)*4096 + imgoff(row, l & 3)) = w;
}

// ------- kernel 2: transpose+convert W -> Bn image + column norms -------
__global__ __launch_bounds__(128)
void transpose_norm_k(const float* __restrict__ Kg, u16* __restrict__ Bn,
                      float* __restrict__ kinv) {
    __shared__ float Ls[32 * 132];
    const int t  = threadIdx.x;
    const int jb = blockIdx.x * 128;
    const int j  = jb + t;
    u16* bstrip = Bn + (size_t)blockIdx.x * 65536;
    float acc = 0.f;
    for (int kc = 0; kc < 16; ++kc) {
        #pragma unroll
        for (int it = 0; it < 8; ++it) {
            int fid  = it * 128 + t;
            int r    = fid >> 5;
            int c4   = (fid & 31) * 4;
            int gcol = jb + c4;
            float4 v;
            if (gcol + 3 < NCLS) {
                v = *(const float4*)(Kg + (kc*32 + r) * NCLS + gcol);
            } else {
                v.x = (gcol + 0 < NCLS) ? Kg[(kc*32 + r)*NCLS + gcol + 0] : 0.f;
                v.y = (gcol + 1 < NCLS) ? Kg[(kc*32 + r)*NCLS + gcol + 1] : 0.f;
                v.z = (gcol + 2 < NCLS) ? Kg[(kc*32 + r)*NCLS + gcol + 2] : 0.f;
                v.w = (gcol + 3 < NCLS) ? Kg[(kc*32 + r)*NCLS + gcol + 3] : 0.f;
            }
            *(float4*)(Ls + r * 132 + c4) = v;
        }
        __syncthreads();
        #pragma unroll
        for (int q = 0; q < 4; ++q) {
            u16 u[8];
            #pragma unroll
            for (int e = 0; e < 8; ++e) {
                float v = Ls[(q*8 + e) * 132 + t];
                acc += v * v;
                u[e] = f2bf(v);
            }
            uint4 w;
            w.x = (u32)u[0] | ((u32)u[1] << 16);
            w.y = (u32)u[2] | ((u32)u[3] << 16);
            w.z = (u32)u[4] | ((u32)u[5] << 16);
            w.w = (u32)u[6] | ((u32)u[7] << 16);
            *(uint4*)(bstrip + kc*4096 + imgoff(t, q)) = w;
        }
        __syncthreads();
    }
    kinv[j] = rsqrtf(fmaxf(acc, 1e-30f));
}

// ---------------- kernel 3: per-row target logit & margins ----------------
__global__ __launch_bounds__(64)
void target_k(const float* __restrict__ Af, const u16* __restrict__ Bn,
              const float* __restrict__ kinv, const int* __restrict__ label,
              float* __restrict__ tgt, float* __restrict__ ctm,
              float* __restrict__ fin) {
    const int i = blockIdx.x, l = threadIdx.x;
    const int lab = label[i];
    float4 a0 = *(const float4*)(Af + i * KDIM + l * 8);
    float4 a1 = *(const float4*)(Af + i * KDIM + l * 8 + 4);
    uint4 bv = *(const uint4*)(Bn + (size_t)(lab >> 7) * 65536
               + (l >> 2) * 4096 + imgoff(lab & 127, l & 3));
    float d = a0.x * bf2f((u16)(bv.x & 0xffff)) + a0.y * bf2f((u16)(bv.x >> 16))
            + a0.z * bf2f((u16)(bv.y & 0xffff)) + a0.w * bf2f((u16)(bv.y >> 16))
            + a1.x * bf2f((u16)(bv.z & 0xffff)) + a1.y * bf2f((u16)(bv.z >> 16))
            + a1.z * bf2f((u16)(bv.w & 0xffff)) + a1.w * bf2f((u16)(bv.w >> 16));
    #pragma unroll
    for (int o = 1; o < 64; o <<= 1) d += __shfl_xor(d, o);
    if (l == 0) {
        float c = d * kinv[lab];
        c = fminf(fmaxf(c, -1.f), 1.f);
        tgt[i] = c;
        float sn = sqrtf(fmaxf(1.f - c*c, 0.f));
        float cm = c * COS_M_C - sn * SIN_M_C;
        ctm[i] = cm;
        fin[i] = (c > THRESH_C) ? cm : (c - MM_C);
    }
}

// ---------------- kernel 4: t_new scalar ----------------
__global__ __launch_bounds__(256)
void tnew_k(const float* __restrict__ tgt, const float* __restrict__ tin,
            float* __restrict__ tnw) {
    __shared__ float red[256];
    const int t = threadIdx.x;
    float s = tgt[t] + tgt[t + 256] + tgt[t + 512] + tgt[t + 768];
    red[t] = s;
    __syncthreads();
    for (int o = 128; o > 0; o >>= 1) {
        if (t < o) red[t] += red[t + o];
        __syncthreads();
    }
    if (t == 0) tnw[0] = red[0] * (0.01f / 1024.f) + 0.99f * tin[0];
}

// ---------------- kernel 5: R8 K-loop + CONTIGUOUS epilogue ----------------
// 128x128 tile, BK=32, 4 waves (2x2), 4 blocks/CU, counted vmcnt.
// Epilogue: per m-fragment, all waves dump acc into a padded 32x132 fp32
// LDS slab (reusing staging LDS), then 256 threads store 16 coalesced
// dwordx4 each (full-line coverage) with margin math fused.
__global__ __launch_bounds__(256, 4)
void gemm_k(const u16* __restrict__ A, const u16* __restrict__ B,
            const float* __restrict__ kinv, const float* __restrict__ ctm,
            const float* __restrict__ fin, const int* __restrict__ label,
            const float* __restrict__ tnwp, float* __restrict__ out) {
    __shared__ __align__(16) u16 As[2][4096];   // 2 x 8 KB
    __shared__ __align__(16) u16 Bs[2][4096];   // 2 x 8 KB
    const int tid  = threadIdx.x;
    const int wave = tid >> 6, lane = tid & 63;

    const int L  = blockIdx.x;
    const int w  = (L & 7) * NSTRIP + (L >> 3);
    const int mt = w & 7;
    const int cs = w >> 3;
    const int m0 = mt * 128;
    const int j0 = cs * 128;
    const int wr = (wave >> 1) * 64;
    const int wc = (wave & 1) * 64;

    f32x4 acc[4][4] = {};

    const u16* gA = A + mt * 65536 + tid * 8;
    const u16* gB = B + (size_t)cs * 65536 + tid * 8;

    const int lr = lane & 15, q = lane >> 4;
    const int aBase = imgoff(wr + lr, q);
    const int bBase = imgoff(wc + lr, q);

#define STAGE(b, kt) do {                                        \
    gld16(gA + (kt)*4096,        &As[b][tid*8]);                 \
    gld16(gA + (kt)*4096 + 2048, &As[b][tid*8 + 2048]);          \
    gld16(gB + (kt)*4096,        &Bs[b][tid*8]);                 \
    gld16(gB + (kt)*4096 + 2048, &Bs[b][tid*8 + 2048]);          \
} while (0)

    STAGE(0, 0);
    #pragma unroll 2
    for (int kt = 0; kt < 16; ++kt) {
        const int cur = kt & 1;
        if (kt < 15) {
            STAGE(cur ^ 1, kt + 1);
            asm volatile("s_waitcnt vmcnt(4)" ::: "memory");
        } else {
            asm volatile("s_waitcnt vmcnt(0)" ::: "memory");
        }
        __builtin_amdgcn_s_barrier();    // buf[cur] fully staged

        bf16x8 af[4], bfr[4];
        #pragma unroll
        for (int m = 0; m < 4; ++m)
            af[m] = *(const bf16x8*)(As[cur] + aBase + m * 512);
        #pragma unroll
        for (int n = 0; n < 4; ++n)
            bfr[n] = *(const bf16x8*)(Bs[cur] + bBase + n * 512);
        asm volatile("s_waitcnt lgkmcnt(0)" ::: "memory");
        __builtin_amdgcn_sched_barrier(0);   // rule 18
        __builtin_amdgcn_s_barrier();        // all waves done reading cur

        #pragma unroll
        for (int m = 0; m < 4; ++m)
            #pragma unroll
            for (int n = 0; n < 4; ++n)
                acc[m][n] = __builtin_amdgcn_mfma_f32_16x16x32_bf16(
                                af[m], bfr[n], acc[m][n], 0, 0, 0);
    }
#undef STAGE

    // ---- contiguous epilogue through LDS slab (32 rows x 132 fp32) ----
    const float tnew = *tnwp;
    float* slab = (float*)As;            // 16.9 KB of the 32 KB staging LDS
    // reader mapping: thread t -> slab row t>>3, col segment (t&7)*16
    const int srd  = tid >> 3;                   // 0..31
    const int cseg = (tid & 7) * 16;             // 0,16,...,112
    #pragma unroll 1
    for (int m = 0; m < 4; ++m) {
        __builtin_amdgcn_s_barrier();            // prev iter's reads done
        // write: acc[m][n][r] -> slab[(wr>>6)*16 + q*4 + r][wc + n*16 + lr]
        const int swr = (wr >> 6) * 16 + q * 4;
        #pragma unroll
        for (int n = 0; n < 4; ++n) {
            const int col = wc + n * 16 + lr;
            #pragma unroll
            for (int r = 0; r < 4; ++r)
                slab[(swr + r) * 132 + col] = acc[m][n][r];
        }
        asm volatile("s_waitcnt lgkmcnt(0)" ::: "memory");
        __builtin_amdgcn_s_barrier();            // all writes visible
        // read + margin + coalesced store: row grow, 16 consecutive cols
        const int grow = m0 + (srd >> 4) * 64 + m * 16 + (srd & 15);
        const int cb   = j0 + cseg;
        const float ct  = ctm[grow];
        const float fv  = fin[grow];
        const int   lab = label[grow];
        float* op = out + (size_t)grow * NCLS + cb;
        #pragma unroll
        for (int v4 = 0; v4 < 4; ++v4) {
            const int c0 = cb + v4 * 4;
            float4 kv4 = *(const float4*)(kinv + c0);
            const float* kvp = (const float*)&kv4;
            float o[4];
            #pragma unroll
            for (int c = 0; c < 4; ++c) {
                float x = slab[srd * 132 + cseg + v4 * 4 + c] * kvp[c];
                x = fminf(fmaxf(x, -1.f), 1.f);
                float v = (x > ct) ? x * (tnew + x) : x;
                v = (c0 + c == lab) ? fv : v;
                o[c] = v * S_C;
            }
            if (c0 + 3 < NCLS) {
                *(float4*)(op + v4 * 4) = make_float4(o[0], o[1], o[2], o[3]);
            } else {
                #pragma unroll
                for (int c = 0; c < 4; ++c)
                    if (c0 + c < NCLS) op[v4 * 4 + c] = o[c];
            }
        }
        asm volatile("s_waitcnt lgkmcnt(0)" ::: "memory");
        __builtin_amdgcn_sched_barrier(0);
    }
}

extern "C" void kernel_launch(void* const* d_in, const int* in_sizes, int n_in,
                              void* d_out, int out_size, void* d_ws, size_t ws_size,
                              hipStream_t stream) {
    const float* emb = (const float*)d_in[0];
    const float* Kg  = (const float*)d_in[1];
    const float* tin = (const float*)d_in[2];
    const int*   lab = (const int*)d_in[3];
    float* out = (float*)d_out;

    char* w = (char*)d_ws;
    u16*   Bn   = (u16*)w;                         // 782*65536*2 = 102,498,304
    u16*   Aw   = (u16*)(w + 102498304);           // 8*65536*2   =   1,048,576
    float* Af   = (float*)(w + 103546880);         // 1024*512*4  =   2,097,152
    float* kinv = (float*)(w + 105644032);         // CPAD*4      =     400,384
    float* tgt  = (float*)(w + 106044416);
    float* ctmv = (float*)(w + 106048512);
    float* finv = (float*)(w + 106052608);
    float* tnw  = (float*)(w + 106056704);

    norm_emb_k<<<NROWS, 64, 0, stream>>>(emb, Af, Aw);
    transpose_norm_k<<<NSTRIP, 128, 0, stream>>>(Kg, Bn, kinv);
    target_k<<<NROWS, 64, 0, stream>>>(Af, Bn, kinv, lab, tgt, ctmv, finv);
    tnew_k<<<1, 256, 0, stream>>>(tgt, tin, tnw);
    gemm_k<<<NWG, 256, 0, stream>>>(
        Aw, Bn, kinv, ctmv, finv, lab, tnw, out);
}

// Round 14
// 470.717 us; speedup vs baseline: 8.9990x; 1.2457x over previous
//
#include <hip/hip_runtime.h>

typedef unsigned short u16;
typedef unsigned int u32;
typedef __attribute__((ext_vector_type(8))) short bf16x8;
typedef __attribute__((ext_vector_type(4))) float f32x4;

#define KDIM   512
#define NROWS  1024
#define NCLS   100000
#define CPAD   100096   // 782*128
#define NSTRIP 782      // 128-wide column strips
#define NMT    8        // 1024/128
#define NWG    (NSTRIP*NMT)   // 6256

#define COS_M_C   0.8775825618903728f
#define SIN_M_C   0.4794255386042030f
#define THRESH_C  (-0.8775825618903728f)
#define MM_C      0.2397127693021015f
#define S_C       64.0f

__device__ __forceinline__ u16 f2bf(float f) {
    u32 x = __float_as_uint(f);
    x += 0x7fffu + ((x >> 16) & 1u);   // RNE
    return (u16)(x >> 16);
}
__device__ __forceinline__ float bf2f(u16 u) {
    return __uint_as_float(((u32)u) << 16);
}
__device__ __forceinline__ u32 pack2(float a, float b) {
    return (u32)f2bf(a) | ((u32)f2bf(b) << 16);
}

// Image geometry (R8-validated, SQ_LDS_BANK_CONFLICT == 0): per (tile, kt)
// an 8 KB block = 128 rows x 32 k bf16 = 64 lines of 128 B. Chunk (r,q) at
// line r>>1, slot ((r&1)*4 + q + (r>>1)) & 7. Fragment m stride = 512 u16.
__device__ __forceinline__ int imgoff(int r, int q) {   // u16 units
    return (r >> 1) * 64 + ((((r & 1) << 2) + q + (r >> 1)) & 7) * 8;
}

__device__ __forceinline__ void gld16(const void* g, void* l) {
    __builtin_amdgcn_global_load_lds(
        (const __attribute__((address_space(1))) void*)g,
        (__attribute__((address_space(3))) void*)l, 16, 0, 0);
}

// ---------------- kernel 1: row-normalize embeddings ----------------
__global__ __launch_bounds__(64)
void norm_emb_k(const float* __restrict__ emb, float* __restrict__ Af,
                u16* __restrict__ Aw) {
    const int i = blockIdx.x, l = threadIdx.x;
    const float* e = emb + i * KDIM;
    float4 v0 = *(const float4*)(e + l * 8);
    float4 v1 = *(const float4*)(e + l * 8 + 4);
    float s = v0.x*v0.x + v0.y*v0.y + v0.z*v0.z + v0.w*v0.w
            + v1.x*v1.x + v1.y*v1.y + v1.z*v1.z + v1.w*v1.w;
    #pragma unroll
    for (int o = 1; o < 64; o <<= 1) s += __shfl_xor(s, o);
    float inv = rsqrtf(s);
    float4 n0 = make_float4(v0.x*inv, v0.y*inv, v0.z*inv, v0.w*inv);
    float4 n1 = make_float4(v1.x*inv, v1.y*inv, v1.z*inv, v1.w*inv);
    *(float4*)(Af + i*KDIM + l*8)     = n0;
    *(float4*)(Af + i*KDIM + l*8 + 4) = n1;
    const int mt = i >> 7, row = i & 127;
    uint4 w;
    w.x = pack2(n0.x, n0.y);
    w.y = pack2(n0.z, n0.w);
    w.z = pack2(n1.x, n1.y);
    w.w = pack2(n1.z, n1.w);
    *(uint4*)(Aw + mt*65536 + (l>>2)*4096 + imgoff(row, l & 3)) = w;
}

// ------- kernel 2: transpose+convert W -> Bn image + column norms -------
__global__ __launch_bounds__(128)
void transpose_norm_k(const float* __restrict__ Kg, u16* __restrict__ Bn,
                      float* __restrict__ kinv) {
    __shared__ float Ls[32 * 132];
    const int t  = threadIdx.x;
    const int jb = blockIdx.x * 128;
    const int j  = jb + t;
    u16* bstrip = Bn + (size_t)blockIdx.x * 65536;
    float acc = 0.f;
    for (int kc = 0; kc < 16; ++kc) {
        #pragma unroll
        for (int it = 0; it < 8; ++it) {
            int fid  = it * 128 + t;
            int r    = fid >> 5;
            int c4   = (fid & 31) * 4;
            int gcol = jb + c4;
            float4 v;
            if (gcol + 3 < NCLS) {
                v = *(const float4*)(Kg + (kc*32 + r) * NCLS + gcol);
            } else {
                v.x = (gcol + 0 < NCLS) ? Kg[(kc*32 + r)*NCLS + gcol + 0] : 0.f;
                v.y = (gcol + 1 < NCLS) ? Kg[(kc*32 + r)*NCLS + gcol + 1] : 0.f;
                v.z = (gcol + 2 < NCLS) ? Kg[(kc*32 + r)*NCLS + gcol + 2] : 0.f;
                v.w = (gcol + 3 < NCLS) ? Kg[(kc*32 + r)*NCLS + gcol + 3] : 0.f;
            }
            *(float4*)(Ls + r * 132 + c4) = v;
        }
        __syncthreads();
        #pragma unroll
        for (int q = 0; q < 4; ++q) {
            u16 u[8];
            #pragma unroll
            for (int e = 0; e < 8; ++e) {
                float v = Ls[(q*8 + e) * 132 + t];
                acc += v * v;
                u[e] = f2bf(v);
            }
            uint4 w;
            w.x = (u32)u[0] | ((u32)u[1] << 16);
            w.y = (u32)u[2] | ((u32)u[3] << 16);
            w.z = (u32)u[4] | ((u32)u[5] << 16);
            w.w = (u32)u[6] | ((u32)u[7] << 16);
            *(uint4*)(bstrip + kc*4096 + imgoff(t, q)) = w;
        }
        __syncthreads();
    }
    kinv[j] = rsqrtf(fmaxf(acc, 1e-30f));
}

// ---------------- kernel 3: per-row target logit & margins ----------------
__global__ __launch_bounds__(64)
void target_k(const float* __restrict__ Af, const u16* __restrict__ Bn,
              const float* __restrict__ kinv, const int* __restrict__ label,
              float* __restrict__ tgt, float* __restrict__ ctm,
              float* __restrict__ fin) {
    const int i = blockIdx.x, l = threadIdx.x;
    const int lab = label[i];
    float4 a0 = *(const float4*)(Af + i * KDIM + l * 8);
    float4 a1 = *(const float4*)(Af + i * KDIM + l * 8 + 4);
    uint4 bv = *(const uint4*)(Bn + (size_t)(lab >> 7) * 65536
               + (l >> 2) * 4096 + imgoff(lab & 127, l & 3));
    float d = a0.x * bf2f((u16)(bv.x & 0xffff)) + a0.y * bf2f((u16)(bv.x >> 16))
            + a0.z * bf2f((u16)(bv.y & 0xffff)) + a0.w * bf2f((u16)(bv.y >> 16))
            + a1.x * bf2f((u16)(bv.z & 0xffff)) + a1.y * bf2f((u16)(bv.z >> 16))
            + a1.z * bf2f((u16)(bv.w & 0xffff)) + a1.w * bf2f((u16)(bv.w >> 16));
    #pragma unroll
    for (int o = 1; o < 64; o <<= 1) d += __shfl_xor(d, o);
    if (l == 0) {
        float c = d * kinv[lab];
        c = fminf(fmaxf(c, -1.f), 1.f);
        tgt[i] = c;
        float sn = sqrtf(fmaxf(1.f - c*c, 0.f));
        float cm = c * COS_M_C - sn * SIN_M_C;
        ctm[i] = cm;
        fin[i] = (c > THRESH_C) ? cm : (c - MM_C);
    }
}

// ---------------- kernel 4: t_new scalar ----------------
__global__ __launch_bounds__(256)
void tnew_k(const float* __restrict__ tgt, const float* __restrict__ tin,
            float* __restrict__ tnw) {
    __shared__ float red[256];
    const int t = threadIdx.x;
    float s = tgt[t] + tgt[t + 256] + tgt[t + 512] + tgt[t + 768];
    red[t] = s;
    __syncthreads();
    for (int o = 128; o > 0; o >>= 1) {
        if (t < o) red[t] += red[t + o];
        __syncthreads();
    }
    if (t == 0) tnw[0] = red[0] * (0.01f / 1024.f) + 0.99f * tin[0];
}

// -------- kernel 5: R8 K-loop + corrected contiguous slab epilogue --------
// Slab: 32 rows x 32 chunks(16B) fp32, chunk (r,c) at phys slot (c+r)&31.
// Reader: thread t -> row t>>3, chunks t&7 + i*8. Per store instruction:
// each 8-lane group = one FULL 128-B line contiguous; per 8-lane group the
// LDS read covers all 8 bank-quads exactly once.
__global__ __launch_bounds__(256, 4)
void gemm_k(const u16* __restrict__ A, const u16* __restrict__ B,
            const float* __restrict__ kinv, const float* __restrict__ ctm,
            const float* __restrict__ fin, const int* __restrict__ label,
            const float* __restrict__ tnwp, float* __restrict__ out) {
    __shared__ __align__(16) u16 SH[16384];     // 32 KB: staging + slab alias
    u16 (*As)[4096] = (u16(*)[4096])SH;         // 2 x 8 KB
    u16 (*Bs)[4096] = (u16(*)[4096])(SH + 8192);
    const int tid  = threadIdx.x;
    const int wave = tid >> 6, lane = tid & 63;

    const int L  = blockIdx.x;
    const int w  = (L & 7) * NSTRIP + (L >> 3);
    const int mt = w & 7;
    const int cs = w >> 3;
    const int m0 = mt * 128;
    const int j0 = cs * 128;
    const int wr = (wave >> 1) * 64;
    const int wc = (wave & 1) * 64;

    f32x4 acc[4][4] = {};

    const u16* gA = A + mt * 65536 + tid * 8;
    const u16* gB = B + (size_t)cs * 65536 + tid * 8;

    const int lr = lane & 15, q = lane >> 4;
    const int aBase = imgoff(wr + lr, q);
    const int bBase = imgoff(wc + lr, q);

#define STAGE(b, kt) do {                                        \
    gld16(gA + (kt)*4096,        &As[b][tid*8]);                 \
    gld16(gA + (kt)*4096 + 2048, &As[b][tid*8 + 2048]);          \
    gld16(gB + (kt)*4096,        &Bs[b][tid*8]);                 \
    gld16(gB + (kt)*4096 + 2048, &Bs[b][tid*8 + 2048]);          \
} while (0)

    STAGE(0, 0);
    #pragma unroll 2
    for (int kt = 0; kt < 16; ++kt) {
        const int cur = kt & 1;
        if (kt < 15) {
            STAGE(cur ^ 1, kt + 1);
            asm volatile("s_waitcnt vmcnt(4)" ::: "memory");
        } else {
            asm volatile("s_waitcnt vmcnt(0)" ::: "memory");
        }
        __builtin_amdgcn_s_barrier();    // buf[cur] fully staged

        bf16x8 af[4], bfr[4];
        #pragma unroll
        for (int m = 0; m < 4; ++m)
            af[m] = *(const bf16x8*)(As[cur] + aBase + m * 512);
        #pragma unroll
        for (int n = 0; n < 4; ++n)
            bfr[n] = *(const bf16x8*)(Bs[cur] + bBase + n * 512);
        asm volatile("s_waitcnt lgkmcnt(0)" ::: "memory");
        __builtin_amdgcn_sched_barrier(0);   // rule 18
        __builtin_amdgcn_s_barrier();        // all waves done reading cur

        #pragma unroll
        for (int m = 0; m < 4; ++m)
            #pragma unroll
            for (int n = 0; n < 4; ++n)
                acc[m][n] = __builtin_amdgcn_mfma_f32_16x16x32_bf16(
                                af[m], bfr[n], acc[m][n], 0, 0, 0);
    }
#undef STAGE

    // ---- epilogue: rotated-chunk slab transpose + full-line stores ----
    const float tnew = *tnwp;
    float* slab = (float*)SH;                    // 32 x 128 fp32 = 16 KB
    const int sr = tid >> 3;                     // reader slab row 0..31
    const int c8 = tid & 7;                      // reader chunk base
    const int swr = (wr >> 6) * 16 + q * 4;      // writer slab row base
    #pragma unroll 1
    for (int m = 0; m < 4; ++m) {
        __builtin_amdgcn_s_barrier();            // prior reads of SH done
        #pragma unroll
        for (int n = 0; n < 4; ++n) {
            const int col = wc + n * 16 + lr;
            const int cw  = col >> 2;
            const int cl  = col & 3;
            #pragma unroll
            for (int r = 0; r < 4; ++r) {
                const int row = swr + r;
                slab[row * 128 + (((cw + row) & 31) << 2) + cl] = acc[m][n][r];
            }
        }
        asm volatile("s_waitcnt lgkmcnt(0)" ::: "memory");
        __builtin_amdgcn_s_barrier();            // all writes visible
        const int grow = m0 + (sr >> 4) * 64 + m * 16 + (sr & 15);
        const float ct  = ctm[grow];
        const float fv  = fin[grow];
        const int   lab = label[grow];
        float* orow = out + (size_t)grow * NCLS;
        #pragma unroll
        for (int i = 0; i < 4; ++i) {
            const int sc16 = c8 + i * 8;
            const int phys = (sc16 + sr) & 31;
            f32x4 vv = *(const f32x4*)(slab + sr * 128 + (phys << 2));
            const int c0 = j0 + sc16 * 4;
            float4 kv4 = *(const float4*)(kinv + c0);
            const float* kvp = (const float*)&kv4;
            float o[4];
            #pragma unroll
            for (int c = 0; c < 4; ++c) {
                float x = vv[c] * kvp[c];
                x = fminf(fmaxf(x, -1.f), 1.f);
                float v = (x > ct) ? x * (tnew + x) : x;
                v = (c0 + c == lab) ? fv : v;
                o[c] = v * S_C;
            }
            if (c0 + 3 < NCLS) {
                *(float4*)(orow + c0) = make_float4(o[0], o[1], o[2], o[3]);
            } else {
                #pragma unroll
                for (int c = 0; c < 4; ++c)
                    if (c0 + c < NCLS) orow[c0 + c] = o[c];
            }
        }
    }
}

extern "C" void kernel_launch(void* const* d_in, const int* in_sizes, int n_in,
                              void* d_out, int out_size, void* d_ws, size_t ws_size,
                              hipStream_t stream) {
    const float* emb = (const float*)d_in[0];
    const float* Kg  = (const float*)d_in[1];
    const float* tin = (const float*)d_in[2];
    const int*   lab = (const int*)d_in[3];
    float* out = (float*)d_out;

    char* w = (char*)d_ws;
    u16*   Bn   = (u16*)w;                         // 782*65536*2 = 102,498,304
    u16*   Aw   = (u16*)(w + 102498304);           // 8*65536*2   =   1,048,576
    float* Af   = (float*)(w + 103546880);         // 1024*512*4  =   2,097,152
    float* kinv = (float*)(w + 105644032);         // CPAD*4      =     400,384
    float* tgt  = (float*)(w + 106044416);
    float* ctmv = (float*)(w + 106048512);
    float* finv = (float*)(w + 106052608);
    float* tnw  = (float*)(w + 106056704);

    norm_emb_k<<<NROWS, 64, 0, stream>>>(emb, Af, Aw);
    transpose_norm_k<<<NSTRIP, 128, 0, stream>>>(Kg, Bn, kinv);
    target_k<<<NROWS, 64, 0, stream>>>(Af, Bn, kinv, lab, tgt, ctmv, finv);
    tnew_k<<<1, 256, 0, stream>>>(tgt, tin, tnw);
    gemm_k<<<NWG, 256, 0, stream>>>(
        Aw, Bn, kinv, ctmv, finv, lab, tnw, out);
}

// Round 15
// 362.438 us; speedup vs baseline: 11.6874x; 1.2988x over previous
//
#include <hip/hip_runtime.h>

typedef unsigned short u16;
typedef unsigned int u32;
typedef __attribute__((ext_vector_type(8))) short bf16x8;
typedef __attribute__((ext_vector_type(4))) float f32x4;

#define KDIM   512
#define NROWS  1024
#define NCLS   100000
#define CPAD   100096   // 391*256 = 782*128
#define NST256 391      // 256-wide strips (image granularity)
#define NST128 782      // 128-wide strips (gemm tile granularity)
#define NMT    8        // 1024/128
#define NWG    (NST128*NMT)   // 6256

#define COS_M_C   0.8775825618903728f
#define SIN_M_C   0.4794255386042030f
#define THRESH_C  (-0.8775825618903728f)
#define MM_C      0.2397127693021015f
#define S_C       64.0f

__device__ __forceinline__ u16 f2bf(float f) {
    u32 x = __float_as_uint(f);
    x += 0x7fffu + ((x >> 16) & 1u);   // RNE
    return (u16)(x >> 16);
}
__device__ __forceinline__ float bf2f(u16 u) {
    return __uint_as_float(((u32)u) << 16);
}
__device__ __forceinline__ u32 pack2(float a, float b) {
    return (u32)f2bf(a) | ((u32)f2bf(b) << 16);
}

// Image geometry (R8-validated, SQ_LDS_BANK_CONFLICT == 0): per (block, ks)
// a 16 KB block = 256 rows x 32 k bf16 = 128 lines of 128 B. Chunk (r,q) at
// line r>>1, slot ((r&1)*4 + q + (r>>1)) & 7. Slot invariant under r += 16
// AND under r += 128 (64 lines, 64%8==0) -> 128-row sub-tiles are self-
// similar: sub-tile s of a 256-row block = byte offset s*8KB, local imgoff.
__device__ __forceinline__ int imgoff(int r, int q) {   // u16 units
    return (r >> 1) * 64 + ((((r & 1) << 2) + q + (r >> 1)) & 7) * 8;
}

__device__ __forceinline__ void gld16(const void* g, void* l) {
    __builtin_amdgcn_global_load_lds(
        (const __attribute__((address_space(1))) void*)g,
        (__attribute__((address_space(3))) void*)l, 16, 0, 0);
}

// A image: [4 mt256][16 ks][256 rows x 32 k]  (131072 u16 per mt256)
// B image: [391 st256][16 ks][256 cols x 32 k] (131072 u16 per strip)

// ---------------- kernel 1: row-normalize embeddings ----------------
__global__ __launch_bounds__(64)
void norm_emb_k(const float* __restrict__ emb, float* __restrict__ Af,
                u16* __restrict__ Aw) {
    const int i = blockIdx.x, l = threadIdx.x;
    const float* e = emb + i * KDIM;
    float4 v0 = *(const float4*)(e + l * 8);
    float4 v1 = *(const float4*)(e + l * 8 + 4);
    float s = v0.x*v0.x + v0.y*v0.y + v0.z*v0.z + v0.w*v0.w
            + v1.x*v1.x + v1.y*v1.y + v1.z*v1.z + v1.w*v1.w;
    #pragma unroll
    for (int o = 1; o < 64; o <<= 1) s += __shfl_xor(s, o);
    float inv = rsqrtf(s);
    float4 n0 = make_float4(v0.x*inv, v0.y*inv, v0.z*inv, v0.w*inv);
    float4 n1 = make_float4(v1.x*inv, v1.y*inv, v1.z*inv, v1.w*inv);
    *(float4*)(Af + i*KDIM + l*8)     = n0;
    *(float4*)(Af + i*KDIM + l*8 + 4) = n1;
    // lane l owns k = l*8..l*8+7 -> ks = l>>2, chunk q = l&3
    const int mt = i >> 8, row = i & 255;
    uint4 w;
    w.x = pack2(n0.x, n0.y);
    w.y = pack2(n0.z, n0.w);
    w.z = pack2(n1.x, n1.y);
    w.w = pack2(n1.z, n1.w);
    *(uint4*)(Aw + mt*131072 + (l>>2)*8192 + imgoff(row, l & 3)) = w;
}

// ------- kernel 2: transpose+convert W [512][100000]f32 -> Bn image + norms
__global__ __launch_bounds__(256)
void transpose_norm_k(const float* __restrict__ Kg, u16* __restrict__ Bn,
                      float* __restrict__ kinv) {
    __shared__ float Ls[32 * 260];           // 32 k-rows x 256 cols, pad 260
    const int t  = threadIdx.x;
    const int jb = blockIdx.x * 256;
    const int j  = jb + t;
    u16* bstrip = Bn + (size_t)blockIdx.x * 131072;
    float acc = 0.f;
    for (int kc = 0; kc < 16; ++kc) {        // kc == ks (32 k each)
        #pragma unroll
        for (int it = 0; it < 8; ++it) {
            int fid  = it * 256 + t;
            int r    = fid >> 6;
            int c4   = (fid & 63) * 4;
            int gcol = jb + c4;
            float4 v;
            if (gcol + 3 < NCLS) {
                v = *(const float4*)(Kg + (kc*32 + r) * NCLS + gcol);
            } else {
                v.x = (gcol + 0 < NCLS) ? Kg[(kc*32 + r)*NCLS + gcol + 0] : 0.f;
                v.y = (gcol + 1 < NCLS) ? Kg[(kc*32 + r)*NCLS + gcol + 1] : 0.f;
                v.z = (gcol + 2 < NCLS) ? Kg[(kc*32 + r)*NCLS + gcol + 2] : 0.f;
                v.w = (gcol + 3 < NCLS) ? Kg[(kc*32 + r)*NCLS + gcol + 3] : 0.f;
            }
            *(float4*)(Ls + r * 260 + c4) = v;
        }
        __syncthreads();
        #pragma unroll
        for (int q = 0; q < 4; ++q) {        // chunk q covers k = kc*32+q*8..
            u16 u[8];
            #pragma unroll
            for (int e = 0; e < 8; ++e) {
                float v = Ls[(q*8 + e) * 260 + t];
                acc += v * v;
                u[e] = f2bf(v);
            }
            uint4 w;
            w.x = (u32)u[0] | ((u32)u[1] << 16);
            w.y = (u32)u[2] | ((u32)u[3] << 16);
            w.z = (u32)u[4] | ((u32)u[5] << 16);
            w.w = (u32)u[6] | ((u32)u[7] << 16);
            *(uint4*)(bstrip + kc*8192 + imgoff(t, q)) = w;
        }
        __syncthreads();
    }
    kinv[j] = rsqrtf(fmaxf(acc, 1e-30f));
}

// ---------------- kernel 3: per-row target logit & margins ----------------
__global__ __launch_bounds__(64)
void target_k(const float* __restrict__ Af, const u16* __restrict__ Bn,
              const float* __restrict__ kinv, const int* __restrict__ label,
              float* __restrict__ tgt, float* __restrict__ ctm,
              float* __restrict__ fin) {
    const int i = blockIdx.x, l = threadIdx.x;
    const int lab = label[i];
    float4 a0 = *(const float4*)(Af + i * KDIM + l * 8);
    float4 a1 = *(const float4*)(Af + i * KDIM + l * 8 + 4);
    uint4 bv = *(const uint4*)(Bn + (size_t)(lab >> 8) * 131072
               + (l >> 2) * 8192 + imgoff(lab & 255, l & 3));
    float d = a0.x * bf2f((u16)(bv.x & 0xffff)) + a0.y * bf2f((u16)(bv.x >> 16))
            + a0.z * bf2f((u16)(bv.y & 0xffff)) + a0.w * bf2f((u16)(bv.y >> 16))
            + a1.x * bf2f((u16)(bv.z & 0xffff)) + a1.y * bf2f((u16)(bv.z >> 16))
            + a1.z * bf2f((u16)(bv.w & 0xffff)) + a1.w * bf2f((u16)(bv.w >> 16));
    #pragma unroll
    for (int o = 1; o < 64; o <<= 1) d += __shfl_xor(d, o);
    if (l == 0) {
        float c = d * kinv[lab];
        c = fminf(fmaxf(c, -1.f), 1.f);
        tgt[i] = c;
        float sn = sqrtf(fmaxf(1.f - c*c, 0.f));
        float cm = c * COS_M_C - sn * SIN_M_C;
        ctm[i] = cm;
        fin[i] = (c > THRESH_C) ? cm : (c - MM_C);
    }
}

// ---------------- kernel 4: t_new scalar ----------------
__global__ __launch_bounds__(256)
void tnew_k(const float* __restrict__ tgt, const float* __restrict__ tin,
            float* __restrict__ tnw) {
    __shared__ float red[256];
    const int t = threadIdx.x;
    float s = tgt[t] + tgt[t + 256] + tgt[t + 512] + tgt[t + 768];
    red[t] = s;
    __syncthreads();
    for (int o = 128; o > 0; o >>= 1) {
        if (t < o) red[t] += red[t + o];
        __syncthreads();
    }
    if (t == 0) tnw[0] = red[0] * (0.01f / 1024.f) + 0.99f * tin[0];
}

// ------ kernel 5: R8 K-loop + SWAPPED-OPERAND MFMA + float4 epilogue ------
// 128x128 tile, BK=32, 4 waves (2x2), 4 blocks/CU, counted vmcnt.
// acc[m][n] = mfma(B_frag, A_frag, acc): D[class][batch] -> per lane
// reg 0..3 = 4 CONSECUTIVE output columns at one row -> direct dwordx4
// stores from registers: 16 store instrs/thread, 64-B sectors, no LDS.
__global__ __launch_bounds__(256, 4)
void gemm_k(const u16* __restrict__ A, const u16* __restrict__ B,
            const float* __restrict__ kinv, const float* __restrict__ ctm,
            const float* __restrict__ fin, const int* __restrict__ label,
            const float* __restrict__ tnwp, float* __restrict__ out) {
    __shared__ __align__(16) u16 As[2][4096];   // 2 x 8 KB
    __shared__ __align__(16) u16 Bs[2][4096];   // 2 x 8 KB
    const int tid  = threadIdx.x;
    const int wave = tid >> 6, lane = tid & 63;

    // XCD-chunked swizzle (6256 = 8*782, exact): mt fast -> B strip shared.
    const int L  = blockIdx.x;
    const int w  = (L & 7) * NST128 + (L >> 3);
    const int mt = w & 7;                // 128-row tile index 0..7
    const int cs = w >> 3;               // 128-col strip index 0..781
    const int m0 = mt * 128;
    const int j0 = cs * 128;
    const int wr = (wave >> 1) * 64;
    const int wc = (wave & 1) * 64;

    f32x4 acc[4][4] = {};

    // sub-tile addressing into 256-row images: per-ks stride 8192 u16,
    // sub-tile (mt&1 / cs&1) at +4096 u16 (slot rotation invariant mod 8).
    const u16* gA = A + (mt >> 1) * 131072 + (mt & 1) * 4096 + tid * 8;
    const u16* gB = B + (size_t)(cs >> 1) * 131072 + (cs & 1) * 4096 + tid * 8;

    const int lr = lane & 15, q = lane >> 4;
    const int aBase = imgoff(wr + lr, q);
    const int bBase = imgoff(wc + lr, q);

#define STAGE(b, kt) do {                                        \
    gld16(gA + (kt)*8192,        &As[b][tid*8]);                 \
    gld16(gA + (kt)*8192 + 2048, &As[b][tid*8 + 2048]);          \
    gld16(gB + (kt)*8192,        &Bs[b][tid*8]);                 \
    gld16(gB + (kt)*8192 + 2048, &Bs[b][tid*8 + 2048]);          \
} while (0)

    STAGE(0, 0);
    #pragma unroll 2
    for (int kt = 0; kt < 16; ++kt) {
        const int cur = kt & 1;
        if (kt < 15) {
            STAGE(cur ^ 1, kt + 1);
            asm volatile("s_waitcnt vmcnt(4)" ::: "memory");
        } else {
            asm volatile("s_waitcnt vmcnt(0)" ::: "memory");
        }
        __builtin_amdgcn_s_barrier();    // buf[cur] fully staged

        bf16x8 af[4], bfr[4];
        #pragma unroll
        for (int m = 0; m < 4; ++m)
            af[m] = *(const bf16x8*)(As[cur] + aBase + m * 512);
        #pragma unroll
        for (int n = 0; n < 4; ++n)
            bfr[n] = *(const bf16x8*)(Bs[cur] + bBase + n * 512);
        asm volatile("s_waitcnt lgkmcnt(0)" ::: "memory");
        __builtin_amdgcn_sched_barrier(0);   // rule 18
        __builtin_amdgcn_s_barrier();        // all waves done reading cur

        // SWAPPED operands: D[class][batch]
        #pragma unroll
        for (int m = 0; m < 4; ++m)
            #pragma unroll
            for (int n = 0; n < 4; ++n)
                acc[m][n] = __builtin_amdgcn_mfma_f32_16x16x32_bf16(
                                bfr[n], af[m], acc[m][n], 0, 0, 0);
    }
#undef STAGE

    // ---- direct-register float4 epilogue ----
    // acc[m][n][c] = out[m0+wr+m*16+(lane&15)][j0+wc+n*16+(lane>>4)*4+c]
    const float tnew = *tnwp;
    const int qd = q * 4;
    float4 kv[4];
    #pragma unroll
    for (int n = 0; n < 4; ++n)
        kv[n] = *(const float4*)(kinv + j0 + wc + n * 16 + qd);
    #pragma unroll
    for (int m = 0; m < 4; ++m) {
        const int row = m0 + wr + m * 16 + lr;
        const float ct  = ctm[row];
        const float fv  = fin[row];
        const int   lab = label[row];
        float* orow = out + (size_t)row * NCLS;
        #pragma unroll
        for (int n = 0; n < 4; ++n) {
            const int c0 = j0 + wc + n * 16 + qd;
            const float* kvp = (const float*)&kv[n];
            float o[4];
            #pragma unroll
            for (int c = 0; c < 4; ++c) {
                float x = acc[m][n][c] * kvp[c];
                x = fminf(fmaxf(x, -1.f), 1.f);
                float v = (x > ct) ? x * (tnew + x) : x;
                v = (c0 + c == lab) ? fv : v;
                o[c] = v * S_C;
            }
            if (c0 < NCLS)   // NCLS % 4 == 0: float4 is all-in or all-out
                *(float4*)(orow + c0) = make_float4(o[0], o[1], o[2], o[3]);
        }
    }
}

extern "C" void kernel_launch(void* const* d_in, const int* in_sizes, int n_in,
                              void* d_out, int out_size, void* d_ws, size_t ws_size,
                              hipStream_t stream) {
    const float* emb = (const float*)d_in[0];
    const float* Kg  = (const float*)d_in[1];
    const float* tin = (const float*)d_in[2];
    const int*   lab = (const int*)d_in[3];
    float* out = (float*)d_out;

    char* w = (char*)d_ws;
    u16*   Bn   = (u16*)w;                         // 391*131072*2 = 102,498,304
    u16*   Aw   = (u16*)(w + 102498304);           // 4*131072*2   =   1,048,576
    float* Af   = (float*)(w + 103546880);         // 1024*512*4   =   2,097,152
    float* kinv = (float*)(w + 105644032);         // CPAD*4       =     400,384
    float* tgt  = (float*)(w + 106044416);
    float* ctmv = (float*)(w + 106048512);
    float* finv = (float*)(w + 106052608);
    float* tnw  = (float*)(w + 106056704);

    norm_emb_k<<<NROWS, 64, 0, stream>>>(emb, Af, Aw);
    transpose_norm_k<<<NST256, 256, 0, stream>>>(Kg, Bn, kinv);
    target_k<<<NROWS, 64, 0, stream>>>(Af, Bn, kinv, lab, tgt, ctmv, finv);
    tnew_k<<<1, 256, 0, stream>>>(tgt, tin, tnw);
    gemm_k<<<NWG, 256, 0, stream>>>(
        Aw, Bn, kinv, ctmv, finv, lab, tnw, out);
}